// Round 1
// baseline (445.559 us; speedup 1.0000x reference)
//
#include <hip/hip_runtime.h>

constexpr int N_NODES  = 50000;
constexpr int N_EDGES  = 1600000;
constexpr int F_IN     = 48;
constexpr int C1_OUT   = 16;

// ---- binning geometry -----------------------------------------------------
constexpr int NB       = 196;                 // coarse bins: bin = dst >> 8 (256 nodes each)
constexpr int CAP      = 9216;                // per-bin capacity: mean 8163, +11.7 sigma
constexpr int BIN_BLKS = 512;
constexpr int EPB      = N_EDGES / BIN_BLKS;  // 3125 edges per bin-block (exact)
constexpr int SCAP     = 48;                  // LDS staging entries per bin (mean ~16, +8 sigma)
constexpr int XW_BLKS  = (N_NODES + 1023) / 1024;   // 49

constexpr int QNODES   = 64;                  // nodes per agg block (quarter bin)
constexpr int AGG_BLKS = NB * 4;              // 784
constexpr int LCAP     = 3072;                // LDS bucket entries per quarter (mean ~2041, +23 sigma)

// ---- workspace layout (~10.4 MB) ------------------------------------------
constexpr size_t GCNT_BYTES = 1024;                                    // NB ints, padded
constexpr size_t PART_BYTES = 4096;                                    // AGG_BLKS floats, padded
constexpr size_t XW_BYTES   = (size_t)N_NODES * C1_OUT * sizeof(float);// 3.2 MB
constexpr size_t BIN_BYTES  = (size_t)NB * CAP * sizeof(int);          // 7.23 MB

// ---------------------------------------------------------------------------
// xw[n] = x[n] @ W  (fold linear map before gather; 3.2 MB table, L2-resident)
// ---------------------------------------------------------------------------
__device__ __forceinline__ void xw_body(int n, const float* __restrict__ x,
                                        const float* __restrict__ W,
                                        float* __restrict__ xw)
{
    const float4* xr = (const float4*)(x + (long)n * F_IN);
    float h[C1_OUT];
    #pragma unroll
    for (int c = 0; c < C1_OUT; ++c) h[c] = 0.f;
    #pragma unroll
    for (int k = 0; k < F_IN / 4; ++k) {
        float4 v = xr[k];
        #pragma unroll
        for (int c = 0; c < C1_OUT; ++c) {
            h[c] = fmaf(v.x, W[(4*k+0)*C1_OUT + c],
                   fmaf(v.y, W[(4*k+1)*C1_OUT + c],
                   fmaf(v.z, W[(4*k+2)*C1_OUT + c],
                   fmaf(v.w, W[(4*k+3)*C1_OUT + c], h[c]))));
        }
    }
    float4* o = (float4*)(xw + (long)n * C1_OUT);
    o[0] = make_float4(h[0],  h[1],  h[2],  h[3]);
    o[1] = make_float4(h[4],  h[5],  h[6],  h[7]);
    o[2] = make_float4(h[8],  h[9],  h[10], h[11]);
    o[3] = make_float4(h[12], h[13], h[14], h[15]);
}

// ---------------------------------------------------------------------------
// Pass 1: LDS-staged coarse binning (+ fused xw in a disjoint block range).
// Entry pack: (src << 8) | (dst & 255). src < 50000 < 2^16, so v < 2^24 >= 0.
// Global atomics: ~NB per block (flush) instead of 1 per edge.
// Flush writes are contiguous runs -> write-combined lines, not 64B/edge.
// ---------------------------------------------------------------------------
__global__ __launch_bounds__(1024)
void k_bin_xw(const int* __restrict__ src, const int* __restrict__ dst,
              int* __restrict__ gcnt, int* __restrict__ gbin,
              const float* __restrict__ x, const float* __restrict__ W,
              float* __restrict__ xw)
{
    __shared__ int lcnt[NB];
    __shared__ int lstage[NB * SCAP];   // 37.6 KB

    if (blockIdx.x >= BIN_BLKS) {       // fused xw range (no barriers executed here)
        int n = (blockIdx.x - BIN_BLKS) * 1024 + threadIdx.x;
        if (n < N_NODES) xw_body(n, x, W, xw);
        return;
    }

    int tid = threadIdx.x;
    for (int b = tid; b < NB; b += 1024) lcnt[b] = 0;
    __syncthreads();

    int e0 = blockIdx.x * EPB;
    #pragma unroll
    for (int k = 0; k < 4; ++k) {
        int i = tid + (k << 10);
        if (i < EPB) {
            int e = e0 + i;
            int s = src[e], d = dst[e];
            int b = d >> 8;
            int v = (s << 8) | (d & 255);
            int p = atomicAdd(&lcnt[b], 1);
            if (p < SCAP) {
                lstage[b * SCAP + p] = v;
            } else {                     // ~impossible overflow; correctness fallback
                int g = atomicAdd(&gcnt[b], 1);
                if (g < CAP) gbin[(long)b * CAP + g] = v;
            }
        }
    }
    __syncthreads();

    int w = tid >> 6, lane = tid & 63;
    for (int b = w; b < NB; b += 16) {   // 16 waves cover 196 bins
        int m = lcnt[b]; if (m > SCAP) m = SCAP;
        if (!m) continue;
        int base = 0;
        if (lane == 0) base = atomicAdd(&gcnt[b], m);
        base = __shfl(base, 0, 64);
        for (int i = lane; i < m; i += 64) {
            int g = base + i;
            if (g < CAP) gbin[(long)b * CAP + g] = lstage[b * SCAP + i];
        }
    }
}

// ---------------------------------------------------------------------------
// Shared epilogue: mean + bias + relu -> 16->8 relu -> 8->1 sigmoid -> p,
// weighted BCE contribution returned on lane 0.
// ---------------------------------------------------------------------------
__device__ __forceinline__ float node_epilogue(
    float4 a, int n, float inv, const float* __restrict__ xw,
    const float* __restrict__ bias, const float* __restrict__ lin1_w,
    const float* __restrict__ lin1_b, const float* __restrict__ out_w,
    const float* __restrict__ out_b, const float* __restrict__ labels,
    const float* __restrict__ weights, float* __restrict__ out,
    float* s16, int lane)
{
    if (lane < 4) {
        float4 v  = ((const float4*)(xw + (long)n * C1_OUT))[lane]; // self loop
        float4 b4 = ((const float4*)bias)[lane];
        float4 h;
        h.x = fmaxf((a.x + v.x) * inv + b4.x, 0.f);
        h.y = fmaxf((a.y + v.y) * inv + b4.y, 0.f);
        h.z = fmaxf((a.z + v.z) * inv + b4.z, 0.f);
        h.w = fmaxf((a.w + v.w) * inv + b4.w, 0.f);
        ((float4*)s16)[lane] = h;
    }
    // same-wave LDS dep: compiler inserts lgkmcnt wait; no barrier needed.
    float x2 = 0.f;
    if (lane < 8) {
        x2 = lin1_b[lane];
        #pragma unroll
        for (int k = 0; k < C1_OUT; ++k)
            x2 = fmaf(s16[k], lin1_w[k * 8 + lane], x2);
        x2 = fmaxf(x2, 0.f) * out_w[lane];
    }
    x2 += __shfl_xor(x2, 1, 64);
    x2 += __shfl_xor(x2, 2, 64);
    x2 += __shfl_xor(x2, 4, 64);
    float ret = 0.f;
    if (lane == 0) {
        float z = x2 + out_b[0];
        float p = 1.f / (1.f + __expf(-z));
        out[1 + n] = p;
        const float eps = 1e-7f;
        float pc = fminf(fmaxf(p, eps), 1.f - eps);
        float y  = labels[n];
        float bce = -(y * __logf(pc) + (1.f - y) * __logf(1.f - pc));
        ret = weights[n] * bce;
    }
    return ret;
}

// ---------------------------------------------------------------------------
// Pass 2: one block per quarter-bin (64 nodes). Rebuild per-node CSR entirely
// in LDS (hist -> wave scan -> scatter), then wave-per-node gather of xw rows
// + fused MLP/loss epilogue. No global bucket, no global atomics.
// ---------------------------------------------------------------------------
__global__ __launch_bounds__(512)
void k_agg_bins(const int* __restrict__ gcnt, const int* __restrict__ gbin,
                const float* __restrict__ xw,
                const float* __restrict__ bias, const float* __restrict__ lin1_w,
                const float* __restrict__ lin1_b, const float* __restrict__ out_w,
                const float* __restrict__ out_b, const float* __restrict__ labels,
                const float* __restrict__ weights, float* __restrict__ out,
                float* __restrict__ partials)
{
    __shared__ int hist[QNODES];
    __shared__ int cursor[QNODES];
    __shared__ unsigned short lbuk[LCAP];   // 6 KB
    __shared__ float s16[8][16];
    __shared__ float sLossW[8];

    int B = blockIdx.x >> 2, Q = blockIdx.x & 3;
    int tid = threadIdx.x, lane = tid & 63, w = tid >> 6;
    int m = gcnt[B]; if (m > CAP) m = CAP;

    if (tid < QNODES) hist[tid] = 0;
    __syncthreads();

    // load this bin's entries once into registers (CAP = 18 * 512 exactly)
    int r[18];
    const int* bb = gbin + (long)B * CAP;
    #pragma unroll
    for (int k = 0; k < 18; ++k) {
        int i = tid + (k << 9);
        r[k] = (i < m) ? bb[i] : -1;     // valid entries are >= 0 (< 2^24)
    }

    // phase 1: histogram this quarter's nodes
    #pragma unroll
    for (int k = 0; k < 18; ++k) {
        int v = r[k];
        if (v >= 0 && ((v >> 6) & 3) == Q)
            atomicAdd(&hist[v & 63], 1);
    }
    __syncthreads();

    // phase 2: exclusive scan of 64 counts (wave 0)
    if (tid < 64) {
        int val = hist[tid];
        int s = val;
        #pragma unroll
        for (int off = 1; off < 64; off <<= 1) {
            int u = __shfl_up(s, off, 64);
            if (lane >= off) s += u;
        }
        cursor[tid] = s - val;           // exclusive prefix
    }
    __syncthreads();

    // phase 3: scatter src indices into LDS CSR
    #pragma unroll
    for (int k = 0; k < 18; ++k) {
        int v = r[k];
        if (v >= 0 && ((v >> 6) & 3) == Q) {
            int p = atomicAdd(&cursor[v & 63], 1);
            if (p < LCAP) lbuk[p] = (unsigned short)(v >> 8);
        }
    }
    __syncthreads();

    // phase 4: wave-per-node aggregate (8 waves x 8 nodes each)
    int rslot = lane >> 2, c4 = lane & 3;
    int nbase = B * 256 + Q * QNODES;
    float wLoss = 0.f;
    for (int i = 0; i < 8; ++i) {
        int ln = w * 8 + i;
        int n = nbase + ln;
        if (n >= N_NODES) break;         // ln increases with i -> safe
        int deg = hist[ln];
        int start = cursor[ln] - deg;    // cursor advanced by exactly deg
        float4 a = make_float4(0.f, 0.f, 0.f, 0.f);
        for (int j0 = 0; j0 < deg; j0 += 16) {
            int j = j0 + rslot;
            if (j < deg) {
                int s = lbuk[start + j];
                float4 v = ((const float4*)(xw + (long)s * C1_OUT))[c4];
                a.x += v.x; a.y += v.y; a.z += v.z; a.w += v.w;
            }
        }
        #pragma unroll
        for (int off = 4; off < 64; off <<= 1) {
            a.x += __shfl_xor(a.x, off, 64);
            a.y += __shfl_xor(a.y, off, 64);
            a.z += __shfl_xor(a.z, off, 64);
            a.w += __shfl_xor(a.w, off, 64);
        }
        wLoss += node_epilogue(a, n, 1.f / (float)(deg + 1), xw, bias, lin1_w,
                               lin1_b, out_w, out_b, labels, weights, out,
                               s16[w], lane);
    }
    if (lane == 0) sLossW[w] = wLoss;
    __syncthreads();
    if (tid == 0) {
        float t = 0.f;
        #pragma unroll
        for (int k = 0; k < 8; ++k) t += sLossW[k];
        partials[blockIdx.x] = t;
    }
}

// ---------------------------------------------------------------------------
// Final loss reduce: one block over 784 partials.
// ---------------------------------------------------------------------------
__global__ __launch_bounds__(1024)
void k_loss_final(const float* __restrict__ partials, float* __restrict__ out)
{
    __shared__ float sw[16];
    int tid = threadIdx.x, lane = tid & 63, wv = tid >> 6;
    float s = (tid < AGG_BLKS) ? partials[tid] : 0.f;
    #pragma unroll
    for (int off = 32; off > 0; off >>= 1) s += __shfl_down(s, off, 64);
    if (lane == 0) sw[wv] = s;
    __syncthreads();
    if (tid == 0) {
        float t = 0.f;
        #pragma unroll
        for (int k = 0; k < 16; ++k) t += sw[k];
        out[0] = t / (float)N_NODES;
    }
}

// ===========================================================================
extern "C" void kernel_launch(void* const* d_in, const int* in_sizes, int n_in,
                              void* d_out, int out_size, void* d_ws, size_t ws_size,
                              hipStream_t stream)
{
    const float* x       = (const float*)d_in[0];
    const int*   eidx    = (const int*)  d_in[1];   // [2, E]
    const float* labels  = (const float*)d_in[2];
    const float* weights = (const float*)d_in[3];
    const float* W       = (const float*)d_in[4];
    // d_in[5] = u, d_in[6] = c: dead — softmax over H=1 axis is identically 1
    const float* bias    = (const float*)d_in[7];
    const float* lin1_w  = (const float*)d_in[8];
    const float* lin1_b  = (const float*)d_in[9];
    const float* out_w   = (const float*)d_in[10];
    const float* out_b   = (const float*)d_in[11];
    float* out = (float*)d_out;

    const int* src = eidx;
    const int* dst = eidx + N_EDGES;
    char* ws = (char*)d_ws;

    int*   gcnt     = (int*)ws;
    float* partials = (float*)(ws + GCNT_BYTES);
    float* xw       = (float*)(ws + GCNT_BYTES + PART_BYTES);
    int*   gbin     = (int*)(ws + GCNT_BYTES + PART_BYTES + XW_BYTES);

    hipMemsetAsync(gcnt, 0, NB * sizeof(int), stream);
    k_bin_xw<<<BIN_BLKS + XW_BLKS, 1024, 0, stream>>>(src, dst, gcnt, gbin, x, W, xw);
    k_agg_bins<<<AGG_BLKS, 512, 0, stream>>>(gcnt, gbin, xw, bias, lin1_w, lin1_b,
                                             out_w, out_b, labels, weights, out, partials);
    k_loss_final<<<1, 1024, 0, stream>>>(partials, out);
}

// Round 2
// 297.842 us; speedup vs baseline: 1.4960x; 1.4960x over previous
//
#include <hip/hip_runtime.h>

constexpr int N_NODES  = 50000;
constexpr int N_EDGES  = 1600000;
constexpr int F_IN     = 48;
constexpr int C1_OUT   = 16;

// ---- binning geometry -----------------------------------------------------
constexpr int NB       = 196;                 // bin = dst >> 8 (256 nodes each)
constexpr int BIN_BLKS = 512;                 // fill blocks; slot table dimension
constexpr int EPB      = N_EDGES / BIN_BLKS;  // 3125 edges per fill block (exact)
constexpr int SCAP     = 48;                  // per-(bin,block) slots: mean 16, +8 sigma
constexpr int OCAP     = 4096;                // global overflow list (expected use: 0)
constexpr int XW_BLKS  = 49;                  // 49*1024 >= 50000
constexpr int AGG_BLKS = NB * 4;              // 784: one block per 64-node quarter-bin

// ---- workspace layout (~18.1 MB; harness provides >= 22.65 MB) ------------
constexpr size_t CNT2D_BYTES = (size_t)NB * BIN_BLKS * sizeof(int);     // 401408
constexpr size_t OCNT_BYTES  = 64;
constexpr size_t OFLOW_BYTES = (size_t)OCAP * 4;                        // 16384
constexpr size_t PART_BYTES  = 4096;                                    // 784 floats
constexpr size_t XW_BYTES    = (size_t)N_NODES * C1_OUT * sizeof(float);// 3.2 MB
constexpr size_t GSRC_BYTES  = (size_t)NB * BIN_BLKS * SCAP * 2;        // 9.63 MB
constexpr size_t GDLO_BYTES  = (size_t)NB * BIN_BLKS * SCAP;            // 4.82 MB

// ---------------------------------------------------------------------------
// xw[n] = x[n] @ W  (fold linear map before gather; 3.2 MB table, L2-resident)
// ---------------------------------------------------------------------------
__device__ __forceinline__ void xw_body(int n, const float* __restrict__ x,
                                        const float* __restrict__ W,
                                        float* __restrict__ xw)
{
    const float4* xr = (const float4*)(x + (long)n * F_IN);
    float h[C1_OUT];
    #pragma unroll
    for (int c = 0; c < C1_OUT; ++c) h[c] = 0.f;
    #pragma unroll
    for (int k = 0; k < F_IN / 4; ++k) {
        float4 v = xr[k];
        #pragma unroll
        for (int c = 0; c < C1_OUT; ++c) {
            h[c] = fmaf(v.x, W[(4*k+0)*C1_OUT + c],
                   fmaf(v.y, W[(4*k+1)*C1_OUT + c],
                   fmaf(v.z, W[(4*k+2)*C1_OUT + c],
                   fmaf(v.w, W[(4*k+3)*C1_OUT + c], h[c]))));
        }
    }
    float4* o = (float4*)(xw + (long)n * C1_OUT);
    o[0] = make_float4(h[0],  h[1],  h[2],  h[3]);
    o[1] = make_float4(h[4],  h[5],  h[6],  h[7]);
    o[2] = make_float4(h[8],  h[9],  h[10], h[11]);
    o[3] = make_float4(h[12], h[13], h[14], h[15]);
}

// ---------------------------------------------------------------------------
// Pass 1: deterministic per-(bin,block) slot scatter. ZERO global atomics.
// Each block's 196 runs span ~28 KB, exclusive to this block -> all its
// scattered 2B/1B stores combine in its XCD's L2 (64 resident blocks x 28 KB
// = 1.8 MB < 4 MB L2) and evict once. Only per-edge cost: 1 LDS atomicAdd.
// xw fused in a disjoint block range.
// ---------------------------------------------------------------------------
__global__ __launch_bounds__(1024)
void k_fill_xw(const int* __restrict__ src, const int* __restrict__ dst,
               int* __restrict__ cnt2d, int* __restrict__ ocnt,
               unsigned int* __restrict__ oflow,
               unsigned short* __restrict__ gsrc, unsigned char* __restrict__ gdlo,
               const float* __restrict__ x, const float* __restrict__ W,
               float* __restrict__ xw)
{
    if (blockIdx.x >= BIN_BLKS) {            // fused xw range
        int n = (blockIdx.x - BIN_BLKS) * 1024 + threadIdx.x;
        if (n < N_NODES) xw_body(n, x, W, xw);
        return;
    }

    __shared__ int lcnt[NB];
    int tid = threadIdx.x;
    if (tid < NB) lcnt[tid] = 0;
    __syncthreads();

    int e0 = blockIdx.x * EPB;
    #pragma unroll
    for (int k = 0; k < 4; ++k) {
        int i = tid + (k << 10);
        if (i < EPB) {
            int e = e0 + i;
            int s = src[e], d = dst[e];
            int b = d >> 8;
            int p = atomicAdd(&lcnt[b], 1);
            if (p < SCAP) {
                int o = (b * BIN_BLKS + blockIdx.x) * SCAP + p;
                gsrc[o] = (unsigned short)s;
                gdlo[o] = (unsigned char)(d & 255);
            } else {                          // ~never (P ~ 1e-4 total); correctness
                int g = atomicAdd(ocnt, 1);
                if (g < OCAP) oflow[g] = ((unsigned)s << 16) | (unsigned)d;
            }
        }
    }
    __syncthreads();
    if (tid < NB) {
        int c = lcnt[tid];
        cnt2d[tid * BIN_BLKS + blockIdx.x] = (c < SCAP) ? c : SCAP;
    }
}

// ---------------------------------------------------------------------------
// Pass 2: one block per 64-node quarter-bin. Stream the bin's 512 runs,
// filter by quarter, accumulate directly into LDS float acc[64][17] with
// ds_add_f32 (fire-and-forget; pad 17 breaks the stride-16 bank pathology).
// No CSR rebuild, no hist/scan/scatter phases, no serial per-node wave loop.
// Epilogue: thread-per-node scalar MLP + one wave shuffle loss reduce.
// ---------------------------------------------------------------------------
__device__ __forceinline__ void acc_row(float (*acc)[17], int* sdeg, int ln,
                                        const float* __restrict__ xw, int s)
{
    const float4* xr = (const float4*)(xw + (long)s * C1_OUT);
    #pragma unroll
    for (int c = 0; c < 4; ++c) {
        float4 v = xr[c];
        atomicAdd(&acc[ln][c * 4 + 0], v.x);
        atomicAdd(&acc[ln][c * 4 + 1], v.y);
        atomicAdd(&acc[ln][c * 4 + 2], v.z);
        atomicAdd(&acc[ln][c * 4 + 3], v.w);
    }
    atomicAdd(&sdeg[ln], 1);
}

__global__ __launch_bounds__(256)
void k_agg(const int* __restrict__ cnt2d, const unsigned short* __restrict__ gsrc,
           const unsigned char* __restrict__ gdlo, const int* __restrict__ ocnt,
           const unsigned int* __restrict__ oflow, const float* __restrict__ xw,
           const float* __restrict__ bias, const float* __restrict__ lin1_w,
           const float* __restrict__ lin1_b, const float* __restrict__ out_w,
           const float* __restrict__ out_b, const float* __restrict__ labels,
           const float* __restrict__ weights, float* __restrict__ out,
           float* __restrict__ partials)
{
    __shared__ float acc[64][17];
    __shared__ int   sdeg[64];

    int B = blockIdx.x >> 2, Q = blockIdx.x & 3;
    int tid = threadIdx.x;

    for (int i = tid; i < 64 * 17; i += 256) ((float*)acc)[i] = 0.f;
    if (tid < 64) sdeg[tid] = 0;
    __syncthreads();

    // main scan: 512 runs, 2 per thread
    #pragma unroll
    for (int rr = 0; rr < 2; ++rr) {
        int run = tid * 2 + rr;
        int m = cnt2d[B * BIN_BLKS + run];
        int base = (B * BIN_BLKS + run) * SCAP;
        for (int i = 0; i < m; ++i) {
            int dl = gdlo[base + i];
            if ((dl >> 6) == Q)
                acc_row(acc, sdeg, dl & 63, xw, gsrc[base + i]);
        }
    }

    // overflow entries (normally zero)
    int oc = *ocnt; if (oc > OCAP) oc = OCAP;
    for (int i = tid; i < oc; i += 256) {
        unsigned v = oflow[i];
        int d = (int)(v & 0xffffu);
        if ((d >> 8) == B && ((d >> 6) & 3) == Q)
            acc_row(acc, sdeg, d & 63, xw, (int)(v >> 16));
    }
    __syncthreads();

    float lw = 0.f;
    if (tid < 64) {
        int n = B * 256 + Q * 64 + tid;
        if (n < N_NODES) {
            float inv = 1.f / (float)(sdeg[tid] + 1);     // +1 = self loop
            const float4* xs4 = (const float4*)(xw + (long)n * C1_OUT);
            float xs[16];
            ((float4*)xs)[0] = xs4[0];
            ((float4*)xs)[1] = xs4[1];
            ((float4*)xs)[2] = xs4[2];
            ((float4*)xs)[3] = xs4[3];
            float h[16];
            #pragma unroll
            for (int c = 0; c < 16; ++c)
                h[c] = fmaxf((acc[tid][c] + xs[c]) * inv + bias[c], 0.f);
            float z = out_b[0];
            #pragma unroll
            for (int j = 0; j < 8; ++j) {
                float t = lin1_b[j];
                #pragma unroll
                for (int k = 0; k < 16; ++k) t = fmaf(h[k], lin1_w[k * 8 + j], t);
                z = fmaf(fmaxf(t, 0.f), out_w[j], z);
            }
            float p = 1.f / (1.f + __expf(-z));
            out[1 + n] = p;
            const float eps = 1e-7f;
            float pc = fminf(fmaxf(p, eps), 1.f - eps);
            float y  = labels[n];
            lw = weights[n] * (-(y * __logf(pc) + (1.f - y) * __logf(1.f - pc)));
        }
        #pragma unroll
        for (int off = 32; off > 0; off >>= 1) lw += __shfl_down(lw, off, 64);
        if (tid == 0) partials[blockIdx.x] = lw;
    }
}

// ---------------------------------------------------------------------------
// Final loss reduce: one block over 784 partials.
// ---------------------------------------------------------------------------
__global__ __launch_bounds__(1024)
void k_loss_final(const float* __restrict__ partials, float* __restrict__ out)
{
    __shared__ float sw[16];
    int tid = threadIdx.x, lane = tid & 63, wv = tid >> 6;
    float s = (tid < AGG_BLKS) ? partials[tid] : 0.f;
    #pragma unroll
    for (int off = 32; off > 0; off >>= 1) s += __shfl_down(s, off, 64);
    if (lane == 0) sw[wv] = s;
    __syncthreads();
    if (tid == 0) {
        float t = 0.f;
        #pragma unroll
        for (int k = 0; k < 16; ++k) t += sw[k];
        out[0] = t / (float)N_NODES;
    }
}

// ===========================================================================
extern "C" void kernel_launch(void* const* d_in, const int* in_sizes, int n_in,
                              void* d_out, int out_size, void* d_ws, size_t ws_size,
                              hipStream_t stream)
{
    const float* x       = (const float*)d_in[0];
    const int*   eidx    = (const int*)  d_in[1];   // [2, E]
    const float* labels  = (const float*)d_in[2];
    const float* weights = (const float*)d_in[3];
    const float* W       = (const float*)d_in[4];
    // d_in[5] = u, d_in[6] = c: dead — softmax over H=1 axis is identically 1
    const float* bias    = (const float*)d_in[7];
    const float* lin1_w  = (const float*)d_in[8];
    const float* lin1_b  = (const float*)d_in[9];
    const float* out_w   = (const float*)d_in[10];
    const float* out_b   = (const float*)d_in[11];
    float* out = (float*)d_out;

    const int* src = eidx;
    const int* dst = eidx + N_EDGES;
    char* ws = (char*)d_ws;

    size_t off = 0;
    int*            cnt2d    = (int*)(ws + off);            off += CNT2D_BYTES;
    int*            ocnt     = (int*)(ws + off);            off += OCNT_BYTES;
    unsigned int*   oflow    = (unsigned int*)(ws + off);   off += OFLOW_BYTES;
    float*          partials = (float*)(ws + off);          off += PART_BYTES;
    float*          xw       = (float*)(ws + off);          off += XW_BYTES;
    unsigned short* gsrc     = (unsigned short*)(ws + off); off += GSRC_BYTES;
    unsigned char*  gdlo     = (unsigned char*)(ws + off);  off += GDLO_BYTES;

    hipMemsetAsync(ocnt, 0, sizeof(int), stream);
    k_fill_xw<<<BIN_BLKS + XW_BLKS, 1024, 0, stream>>>(
        src, dst, cnt2d, ocnt, oflow, gsrc, gdlo, x, W, xw);
    k_agg<<<AGG_BLKS, 256, 0, stream>>>(
        cnt2d, gsrc, gdlo, ocnt, oflow, xw, bias, lin1_w, lin1_b,
        out_w, out_b, labels, weights, out, partials);
    k_loss_final<<<1, 1024, 0, stream>>>(partials, out);
}

// Round 3
// 295.668 us; speedup vs baseline: 1.5070x; 1.0074x over previous
//
#include <hip/hip_runtime.h>

constexpr int N_NODES  = 50000;
constexpr int N_EDGES  = 1600000;
constexpr int F_IN     = 48;
constexpr int C1_OUT   = 16;

// ---- binning geometry -----------------------------------------------------
constexpr int BNODES    = 128;                    // nodes per bin; bin = dst >> 7
constexpr int NBINS     = 391;                    // ceil(50000/128)
constexpr int FILL_BLKS = 256;
constexpr int EPB       = N_EDGES / FILL_BLKS;    // 6250 (exact)
constexpr int SCAP      = 32;                     // slots per (bin,block) cell: mean 16
constexpr int OCAP      = 8192;                   // overflow list (expected ~20 entries)
constexpr int XW_BLKS   = 49;                     // 49*1024 >= 50000
constexpr int BIN_INTS  = FILL_BLKS * SCAP;       // 8192 ints per bin (32 KB, contiguous)

// ---- workspace layout (~16.05 MB; all offsets 256B-aligned) ----------------
constexpr size_t OCNT_OFF   = 0;
constexpr size_t OFLOW_OFF  = 256;
constexpr size_t PART_OFF   = OFLOW_OFF + (size_t)OCAP * 4;        // 33024
constexpr size_t XW_OFF     = PART_OFF + 4096;                     // 37120
constexpr size_t GSLOT_OFF  = XW_OFF + (size_t)N_NODES * C1_OUT * 4;
constexpr size_t GSLOT_INTS = (size_t)NBINS * BIN_INTS;            // 3,203,072

// ---------------------------------------------------------------------------
// xw[n] = x[n] @ W  (fold linear map before gather; 3.2 MB table)
// ---------------------------------------------------------------------------
__device__ __forceinline__ void xw_body(int n, const float* __restrict__ x,
                                        const float* __restrict__ W,
                                        float* __restrict__ xw)
{
    const float4* xr = (const float4*)(x + (long)n * F_IN);
    float h[C1_OUT];
    #pragma unroll
    for (int c = 0; c < C1_OUT; ++c) h[c] = 0.f;
    #pragma unroll
    for (int k = 0; k < F_IN / 4; ++k) {
        float4 v = xr[k];
        #pragma unroll
        for (int c = 0; c < C1_OUT; ++c) {
            h[c] = fmaf(v.x, W[(4*k+0)*C1_OUT + c],
                   fmaf(v.y, W[(4*k+1)*C1_OUT + c],
                   fmaf(v.z, W[(4*k+2)*C1_OUT + c],
                   fmaf(v.w, W[(4*k+3)*C1_OUT + c], h[c]))));
        }
    }
    float4* o = (float4*)(xw + (long)n * C1_OUT);
    o[0] = make_float4(h[0],  h[1],  h[2],  h[3]);
    o[1] = make_float4(h[4],  h[5],  h[6],  h[7]);
    o[2] = make_float4(h[8],  h[9],  h[10], h[11]);
    o[3] = make_float4(h[12], h[13], h[14], h[15]);
}

// ---------------------------------------------------------------------------
// Pass 1: deterministic per-(bin,block) slot scatter, ZERO global atomics.
// One packed 4B int per edge: (src<<7)|(dst&127); invalid slots padded -1.
// Cells are 128B-aligned and block-exclusive -> L2 write-combining works.
// xw fused in a disjoint block range.
// ---------------------------------------------------------------------------
__global__ __launch_bounds__(1024)
void k_fill_xw(const int* __restrict__ src, const int* __restrict__ dst,
               int* __restrict__ gslot, int* __restrict__ ocnt,
               unsigned int* __restrict__ oflow,
               const float* __restrict__ x, const float* __restrict__ W,
               float* __restrict__ xw)
{
    __shared__ int lcnt[NBINS];

    if (blockIdx.x >= FILL_BLKS) {               // fused xw range
        int n = (blockIdx.x - FILL_BLKS) * 1024 + threadIdx.x;
        if (n < N_NODES) xw_body(n, x, W, xw);
        return;
    }

    int tid = threadIdx.x;
    if (tid < NBINS) lcnt[tid] = 0;
    __syncthreads();

    int e0 = blockIdx.x * EPB;
    for (int i = tid; i < EPB; i += 1024) {
        int e = e0 + i;
        int s = src[e], d = dst[e];
        int b = d >> 7;
        int p = atomicAdd(&lcnt[b], 1);
        if (p < SCAP) {
            gslot[(size_t)(b * FILL_BLKS + blockIdx.x) * SCAP + p] = (s << 7) | (d & 127);
        } else {                                  // rare (~20 edges total)
            int g = atomicAdd(ocnt, 1);
            if (g < OCAP) oflow[g] = ((unsigned)s << 16) | (unsigned)d;
        }
    }
    __syncthreads();

    // pad unused slots with -1 so pass 2 can read blindly (no counts)
    for (int idx = tid; idx < NBINS * SCAP; idx += 1024) {
        int b = idx >> 5, slot = idx & 31;
        if (slot >= lcnt[b])
            gslot[(size_t)(b * FILL_BLKS + blockIdx.x) * SCAP + slot] = -1;
    }
}

// ---------------------------------------------------------------------------
// Pass 2: one block per bin (128 nodes). Blind coalesced int4 read of the
// bin's 8192 slots (fixed trip count), per-edge 64B xw gather + 17
// fire-and-forget LDS atomics into acc[128][17] (stride 17 -> no bank
// pathology). Epilogue fused: per-node MLP + loss partial, no global acc.
// ---------------------------------------------------------------------------
__device__ __forceinline__ void edge_acc(int v, const float* __restrict__ xw,
                                         float (*acc)[17])
{
    if (v < 0) return;
    int s  = v >> 7;
    int ln = v & 127;
    const float4* xr = (const float4*)(xw + (size_t)s * C1_OUT);
    float4 a = xr[0], b = xr[1], c = xr[2], d = xr[3];
    atomicAdd(&acc[ln][0],  a.x); atomicAdd(&acc[ln][1],  a.y);
    atomicAdd(&acc[ln][2],  a.z); atomicAdd(&acc[ln][3],  a.w);
    atomicAdd(&acc[ln][4],  b.x); atomicAdd(&acc[ln][5],  b.y);
    atomicAdd(&acc[ln][6],  b.z); atomicAdd(&acc[ln][7],  b.w);
    atomicAdd(&acc[ln][8],  c.x); atomicAdd(&acc[ln][9],  c.y);
    atomicAdd(&acc[ln][10], c.z); atomicAdd(&acc[ln][11], c.w);
    atomicAdd(&acc[ln][12], d.x); atomicAdd(&acc[ln][13], d.y);
    atomicAdd(&acc[ln][14], d.z); atomicAdd(&acc[ln][15], d.w);
    atomicAdd(&acc[ln][16], 1.0f);               // degree
}

__global__ __launch_bounds__(512)
void k_agg(const int* __restrict__ gslot, const int* __restrict__ ocnt,
           const unsigned int* __restrict__ oflow, const float* __restrict__ xw,
           const float* __restrict__ bias, const float* __restrict__ lin1_w,
           const float* __restrict__ lin1_b, const float* __restrict__ out_w,
           const float* __restrict__ out_b, const float* __restrict__ labels,
           const float* __restrict__ weights, float* __restrict__ out,
           float* __restrict__ partials)
{
    __shared__ float acc[BNODES][17];            // [...][16] = degree
    __shared__ float sLossW[2];

    int B = blockIdx.x, tid = threadIdx.x;

    for (int i = tid; i < BNODES * 17; i += 512) ((float*)acc)[i] = 0.f;
    __syncthreads();

    // blind coalesced scan: 8192 ints = 2048 int4, 4 per thread
    const int4* sp = (const int4*)(gslot + (size_t)B * BIN_INTS);
    int4 q0 = sp[tid], q1 = sp[tid + 512], q2 = sp[tid + 1024], q3 = sp[tid + 1536];
    edge_acc(q0.x, xw, acc); edge_acc(q0.y, xw, acc);
    edge_acc(q0.z, xw, acc); edge_acc(q0.w, xw, acc);
    edge_acc(q1.x, xw, acc); edge_acc(q1.y, xw, acc);
    edge_acc(q1.z, xw, acc); edge_acc(q1.w, xw, acc);
    edge_acc(q2.x, xw, acc); edge_acc(q2.y, xw, acc);
    edge_acc(q2.z, xw, acc); edge_acc(q2.w, xw, acc);
    edge_acc(q3.x, xw, acc); edge_acc(q3.y, xw, acc);
    edge_acc(q3.z, xw, acc); edge_acc(q3.w, xw, acc);

    // overflow entries (normally ~20 total)
    int oc = *ocnt; if (oc > OCAP) oc = OCAP;
    for (int i = tid; i < oc; i += 512) {
        unsigned v = oflow[i];
        int d = (int)(v & 0xffffu);
        if ((d >> 7) == B) {
            int s = (int)(v >> 16);
            edge_acc((s << 7) | (d & 127), xw, acc);
        }
    }
    __syncthreads();

    // fused epilogue: threads 0..127 -> one node each
    float lw = 0.f;
    if (tid < BNODES) {
        int n = B * BNODES + tid;
        if (n < N_NODES) {
            float inv = 1.f / (acc[tid][16] + 1.f);          // +1 self loop
            const float4* xs4 = (const float4*)(xw + (size_t)n * C1_OUT);
            float xs[16];
            ((float4*)xs)[0] = xs4[0]; ((float4*)xs)[1] = xs4[1];
            ((float4*)xs)[2] = xs4[2]; ((float4*)xs)[3] = xs4[3];
            float h[16];
            #pragma unroll
            for (int c = 0; c < 16; ++c)
                h[c] = fmaxf(fmaf(acc[tid][c] + xs[c], inv, bias[c]), 0.f);
            float z = out_b[0];
            #pragma unroll
            for (int j = 0; j < 8; ++j) {
                float t = lin1_b[j];
                #pragma unroll
                for (int k = 0; k < 16; ++k) t = fmaf(h[k], lin1_w[k * 8 + j], t);
                z = fmaf(fmaxf(t, 0.f), out_w[j], z);
            }
            float p = 1.f / (1.f + __expf(-z));
            out[1 + n] = p;
            const float eps = 1e-7f;
            float pc = fminf(fmaxf(p, eps), 1.f - eps);
            float y  = labels[n];
            lw = weights[n] * (-(y * __logf(pc) + (1.f - y) * __logf(1.f - pc)));
        }
        #pragma unroll
        for (int off = 32; off > 0; off >>= 1) lw += __shfl_down(lw, off, 64);
        if ((tid & 63) == 0) sLossW[tid >> 6] = lw;
    }
    __syncthreads();
    if (tid == 0) partials[B] = sLossW[0] + sLossW[1];
}

// ---------------------------------------------------------------------------
// Final loss reduce: one block over 391 partials.
// ---------------------------------------------------------------------------
__global__ __launch_bounds__(512)
void k_loss_final(const float* __restrict__ partials, float* __restrict__ out)
{
    __shared__ float sw[8];
    int tid = threadIdx.x, lane = tid & 63, wv = tid >> 6;
    float s = (tid < NBINS) ? partials[tid] : 0.f;
    #pragma unroll
    for (int off = 32; off > 0; off >>= 1) s += __shfl_down(s, off, 64);
    if (lane == 0) sw[wv] = s;
    __syncthreads();
    if (tid == 0) {
        float t = 0.f;
        #pragma unroll
        for (int k = 0; k < 8; ++k) t += sw[k];
        out[0] = t / (float)N_NODES;
    }
}

// ===========================================================================
extern "C" void kernel_launch(void* const* d_in, const int* in_sizes, int n_in,
                              void* d_out, int out_size, void* d_ws, size_t ws_size,
                              hipStream_t stream)
{
    const float* x       = (const float*)d_in[0];
    const int*   eidx    = (const int*)  d_in[1];   // [2, E]
    const float* labels  = (const float*)d_in[2];
    const float* weights = (const float*)d_in[3];
    const float* W       = (const float*)d_in[4];
    // d_in[5] = u, d_in[6] = c: dead — softmax over H=1 axis is identically 1
    const float* bias    = (const float*)d_in[7];
    const float* lin1_w  = (const float*)d_in[8];
    const float* lin1_b  = (const float*)d_in[9];
    const float* out_w   = (const float*)d_in[10];
    const float* out_b   = (const float*)d_in[11];
    float* out = (float*)d_out;

    const int* src = eidx;
    const int* dst = eidx + N_EDGES;
    char* ws = (char*)d_ws;

    int*          ocnt     = (int*)(ws + OCNT_OFF);
    unsigned int* oflow    = (unsigned int*)(ws + OFLOW_OFF);
    float*        partials = (float*)(ws + PART_OFF);
    float*        xw       = (float*)(ws + XW_OFF);
    int*          gslot    = (int*)(ws + GSLOT_OFF);

    hipMemsetAsync(ocnt, 0, sizeof(int), stream);
    k_fill_xw<<<FILL_BLKS + XW_BLKS, 1024, 0, stream>>>(
        src, dst, gslot, ocnt, oflow, x, W, xw);
    k_agg<<<NBINS, 512, 0, stream>>>(
        gslot, ocnt, oflow, xw, bias, lin1_w, lin1_b,
        out_w, out_b, labels, weights, out, partials);
    k_loss_final<<<1, 512, 0, stream>>>(partials, out);
}

// Round 4
// 149.823 us; speedup vs baseline: 2.9739x; 1.9735x over previous
//
#include <hip/hip_runtime.h>

constexpr int N_NODES  = 50000;
constexpr int N_EDGES  = 1600000;
constexpr int F_IN     = 48;
constexpr int C1_OUT   = 16;

// ---- binning geometry -----------------------------------------------------
constexpr int BNODES    = 128;                    // nodes per bin; bin = dst >> 7
constexpr int NBINS     = 391;                    // ceil(50000/128)
constexpr int FILL_BLKS = 256;
constexpr int EPB       = N_EDGES / FILL_BLKS;    // 6250 (exact)
constexpr int SCAP      = 32;                     // slots per (bin,block) cell: mean 16
constexpr int OCAP      = 8192;                   // overflow list (expected ~<10 entries)
constexpr int BIN_INTS  = FILL_BLKS * SCAP;       // 8192 ints per bin (32 KB contiguous)
constexpr int LCAP      = 6144;                   // LDS CSR entries per bin: mean 4096, +32 sigma

// ---- workspace layout (~16.05 MB; offsets 256B-aligned) --------------------
constexpr size_t OCNT_OFF   = 0;
constexpr size_t OFLOW_OFF  = 256;
constexpr size_t PART_OFF   = OFLOW_OFF + (size_t)OCAP * 4;
constexpr size_t XW_OFF     = PART_OFF + 4096;
constexpr size_t GSLOT_OFF  = XW_OFF + (size_t)N_NODES * C1_OUT * 4;
constexpr size_t GSLOT_BYTES = (size_t)NBINS * BIN_INTS * 4;       // 12.8 MB

// ---------------------------------------------------------------------------
// xw[n] = x[n] @ W  (fold linear map before gather; 3.2 MB table)
// ---------------------------------------------------------------------------
__device__ __forceinline__ void xw_body(int n, const float* __restrict__ x,
                                        const float* __restrict__ W,
                                        float* __restrict__ xw)
{
    const float4* xr = (const float4*)(x + (long)n * F_IN);
    float h[C1_OUT];
    #pragma unroll
    for (int c = 0; c < C1_OUT; ++c) h[c] = 0.f;
    #pragma unroll
    for (int k = 0; k < F_IN / 4; ++k) {
        float4 v = xr[k];
        #pragma unroll
        for (int c = 0; c < C1_OUT; ++c) {
            h[c] = fmaf(v.x, W[(4*k+0)*C1_OUT + c],
                   fmaf(v.y, W[(4*k+1)*C1_OUT + c],
                   fmaf(v.z, W[(4*k+2)*C1_OUT + c],
                   fmaf(v.w, W[(4*k+3)*C1_OUT + c], h[c]))));
        }
    }
    float4* o = (float4*)(xw + (long)n * C1_OUT);
    o[0] = make_float4(h[0],  h[1],  h[2],  h[3]);
    o[1] = make_float4(h[4],  h[5],  h[6],  h[7]);
    o[2] = make_float4(h[8],  h[9],  h[10], h[11]);
    o[3] = make_float4(h[12], h[13], h[14], h[15]);
}

// ---------------------------------------------------------------------------
// Pass 1: deterministic per-(bin,block) slot scatter, ZERO global atomics.
// One packed 4B int per edge: (src<<7)|(dst&127). gslot pre-memset to -1
// (0xFF bytes) so no in-kernel padding. xw fused in disjoint block range.
// ---------------------------------------------------------------------------
constexpr int XW_BLKS = 49;                       // 49*1024 >= 50000

__global__ __launch_bounds__(1024)
void k_fill_xw(const int* __restrict__ src, const int* __restrict__ dst,
               int* __restrict__ gslot, int* __restrict__ ocnt,
               unsigned int* __restrict__ oflow,
               const float* __restrict__ x, const float* __restrict__ W,
               float* __restrict__ xw)
{
    __shared__ int lcnt[NBINS];

    if (blockIdx.x >= FILL_BLKS) {               // fused xw range
        int n = (blockIdx.x - FILL_BLKS) * 1024 + threadIdx.x;
        if (n < N_NODES) xw_body(n, x, W, xw);
        return;
    }

    int tid = threadIdx.x;
    if (tid < NBINS) lcnt[tid] = 0;
    __syncthreads();

    int e0 = blockIdx.x * EPB;
    for (int i = tid; i < EPB; i += 1024) {
        int e = e0 + i;
        int s = src[e], d = dst[e];
        int b = d >> 7;
        int p = atomicAdd(&lcnt[b], 1);
        if (p < SCAP) {
            gslot[(size_t)(b * FILL_BLKS + blockIdx.x) * SCAP + p] = (s << 7) | (d & 127);
        } else {                                  // rare (~few edges total)
            int g = atomicAdd(ocnt, 1);
            if (g < OCAP) oflow[g] = ((unsigned)s << 16) | (unsigned)d;
        }
    }
}

// ---------------------------------------------------------------------------
// Pass 2: one block (512 thr) per bin (128 nodes).
//   A: blind coalesced int4 read of 8192 slots -> registers.
//   B: LDS CSR rebuild: int hist (1 atomic/edge) -> 2-wave scan ->
//      cursor scatter (1 atomic + 1 ds_write/edge). No fp atomics anywhere.
//   C: wave-per-node register aggregation (16 rslots x 4 chunks) + shuffle
//      reduce + fused MLP/loss epilogue.
// ---------------------------------------------------------------------------
__device__ __forceinline__ float node_epilogue(
    float4 a, int n, float inv, const float* __restrict__ xw,
    const float* __restrict__ bias, const float* __restrict__ lin1_w,
    const float* __restrict__ lin1_b, const float* __restrict__ out_w,
    const float* __restrict__ out_b, const float* __restrict__ labels,
    const float* __restrict__ weights, float* __restrict__ out,
    float* s16, int lane)
{
    if (lane < 4) {
        float4 v  = ((const float4*)(xw + (size_t)n * C1_OUT))[lane]; // self loop
        float4 b4 = ((const float4*)bias)[lane];
        float4 h;
        h.x = fmaxf(fmaf(a.x + v.x, inv, b4.x), 0.f);
        h.y = fmaxf(fmaf(a.y + v.y, inv, b4.y), 0.f);
        h.z = fmaxf(fmaf(a.z + v.z, inv, b4.z), 0.f);
        h.w = fmaxf(fmaf(a.w + v.w, inv, b4.w), 0.f);
        ((float4*)s16)[lane] = h;
    }
    // same-wave LDS dep: DS ops retire in order; pattern proven in R0-R2.
    float x2 = 0.f;
    if (lane < 8) {
        x2 = lin1_b[lane];
        #pragma unroll
        for (int k = 0; k < C1_OUT; ++k)
            x2 = fmaf(s16[k], lin1_w[k * 8 + lane], x2);
        x2 = fmaxf(x2, 0.f) * out_w[lane];
    }
    x2 += __shfl_xor(x2, 1, 64);
    x2 += __shfl_xor(x2, 2, 64);
    x2 += __shfl_xor(x2, 4, 64);
    float ret = 0.f;
    if (lane == 0) {
        float z = x2 + out_b[0];
        float p = 1.f / (1.f + __expf(-z));
        out[1 + n] = p;
        const float eps = 1e-7f;
        float pc = fminf(fmaxf(p, eps), 1.f - eps);
        float y  = labels[n];
        ret = weights[n] * (-(y * __logf(pc) + (1.f - y) * __logf(1.f - pc)));
    }
    return ret;
}

__global__ __launch_bounds__(512)
void k_agg(const int* __restrict__ gslot, const int* __restrict__ ocnt,
           const unsigned int* __restrict__ oflow, const float* __restrict__ xw,
           const float* __restrict__ bias, const float* __restrict__ lin1_w,
           const float* __restrict__ lin1_b, const float* __restrict__ out_w,
           const float* __restrict__ out_b, const float* __restrict__ labels,
           const float* __restrict__ weights, float* __restrict__ out,
           float* __restrict__ partials)
{
    __shared__ int   hist[BNODES];
    __shared__ int   cursor[BNODES];
    __shared__ unsigned short lbuk[LCAP];        // 12 KB
    __shared__ float s16[8][16];
    __shared__ float sLossW[8];
    __shared__ int   sHalf;

    int B = blockIdx.x, tid = threadIdx.x, lane = tid & 63, w = tid >> 6;

    if (tid < BNODES) hist[tid] = 0;
    __syncthreads();

    // A: blind coalesced load of the bin's 8192 slots (2048 int4)
    const int4* sp = (const int4*)(gslot + (size_t)B * BIN_INTS);
    int4 q0 = sp[tid], q1 = sp[tid + 512], q2 = sp[tid + 1024], q3 = sp[tid + 1536];

    int oc = *ocnt; if (oc > OCAP) oc = OCAP;

    // B1: histogram (1 int LDS atomic per valid edge)
    #define H1(v) if ((v) >= 0) atomicAdd(&hist[(v) & 127], 1)
    H1(q0.x); H1(q0.y); H1(q0.z); H1(q0.w);
    H1(q1.x); H1(q1.y); H1(q1.z); H1(q1.w);
    H1(q2.x); H1(q2.y); H1(q2.z); H1(q2.w);
    H1(q3.x); H1(q3.y); H1(q3.z); H1(q3.w);
    #undef H1
    for (int i = tid; i < oc; i += 512) {
        int d = (int)(oflow[i] & 0xffffu);
        if ((d >> 7) == B) atomicAdd(&hist[d & 127], 1);
    }
    __syncthreads();

    // B2: exclusive scan of 128 counts (two waves, one half each)
    if (tid < 128) {
        int val = hist[tid];
        int s = val;
        #pragma unroll
        for (int off = 1; off < 64; off <<= 1) {
            int u = __shfl_up(s, off, 64);
            if (lane >= off) s += u;
        }
        cursor[tid] = s - val;
        if (tid == 63) sHalf = s;
    }
    __syncthreads();
    if (tid >= 64 && tid < 128) cursor[tid] += sHalf;
    __syncthreads();

    // B3: scatter src into LDS CSR (1 int atomic + 1 ds_write per edge)
    #define SC(v) if ((v) >= 0) { int p = atomicAdd(&cursor[(v) & 127], 1); \
                                  if (p < LCAP) lbuk[p] = (unsigned short)((unsigned)(v) >> 7); }
    SC(q0.x); SC(q0.y); SC(q0.z); SC(q0.w);
    SC(q1.x); SC(q1.y); SC(q1.z); SC(q1.w);
    SC(q2.x); SC(q2.y); SC(q2.z); SC(q2.w);
    SC(q3.x); SC(q3.y); SC(q3.z); SC(q3.w);
    #undef SC
    for (int i = tid; i < oc; i += 512) {
        unsigned v = oflow[i];
        int d = (int)(v & 0xffffu);
        if ((d >> 7) == B) {
            int p = atomicAdd(&cursor[d & 127], 1);
            if (p < LCAP) lbuk[p] = (unsigned short)(v >> 16);
        }
    }
    __syncthreads();

    // C: wave-per-node register aggregation; 8 waves x 16 nodes
    int rslot = lane >> 2, c4 = lane & 3;
    float lossw = 0.f;
    for (int i = 0; i < 16; ++i) {
        int ln = w * 16 + i;
        int n = B * BNODES + ln;
        if (n >= N_NODES) break;                 // wave-uniform
        int deg   = hist[ln];
        int start = cursor[ln] - deg;            // cursor advanced by exactly deg
        float4 a = make_float4(0.f, 0.f, 0.f, 0.f);
        for (int j0 = 0; j0 < deg; j0 += 16) {
            int j = j0 + rslot;
            if (j < deg && start + j < LCAP) {
                int s = lbuk[start + j];
                float4 v = ((const float4*)(xw + (size_t)s * C1_OUT))[c4];
                a.x += v.x; a.y += v.y; a.z += v.z; a.w += v.w;
            }
        }
        #pragma unroll
        for (int off = 4; off < 64; off <<= 1) {
            a.x += __shfl_xor(a.x, off, 64);
            a.y += __shfl_xor(a.y, off, 64);
            a.z += __shfl_xor(a.z, off, 64);
            a.w += __shfl_xor(a.w, off, 64);
        }
        lossw += node_epilogue(a, n, 1.f / (float)(deg + 1), xw, bias, lin1_w,
                               lin1_b, out_w, out_b, labels, weights, out,
                               s16[w], lane);
    }
    if (lane == 0) sLossW[w] = lossw;
    __syncthreads();
    if (tid == 0) {
        float t = 0.f;
        #pragma unroll
        for (int k = 0; k < 8; ++k) t += sLossW[k];
        partials[B] = t;
    }
}

// ---------------------------------------------------------------------------
// Final loss reduce: one block over 391 partials.
// ---------------------------------------------------------------------------
__global__ __launch_bounds__(512)
void k_loss_final(const float* __restrict__ partials, float* __restrict__ out)
{
    __shared__ float sw[8];
    int tid = threadIdx.x, lane = tid & 63, wv = tid >> 6;
    float s = (tid < NBINS) ? partials[tid] : 0.f;
    #pragma unroll
    for (int off = 32; off > 0; off >>= 1) s += __shfl_down(s, off, 64);
    if (lane == 0) sw[wv] = s;
    __syncthreads();
    if (tid == 0) {
        float t = 0.f;
        #pragma unroll
        for (int k = 0; k < 8; ++k) t += sw[k];
        out[0] = t / (float)N_NODES;
    }
}

// ===========================================================================
extern "C" void kernel_launch(void* const* d_in, const int* in_sizes, int n_in,
                              void* d_out, int out_size, void* d_ws, size_t ws_size,
                              hipStream_t stream)
{
    const float* x       = (const float*)d_in[0];
    const int*   eidx    = (const int*)  d_in[1];   // [2, E]
    const float* labels  = (const float*)d_in[2];
    const float* weights = (const float*)d_in[3];
    const float* W       = (const float*)d_in[4];
    // d_in[5] = u, d_in[6] = c: dead — softmax over H=1 axis is identically 1
    const float* bias    = (const float*)d_in[7];
    const float* lin1_w  = (const float*)d_in[8];
    const float* lin1_b  = (const float*)d_in[9];
    const float* out_w   = (const float*)d_in[10];
    const float* out_b   = (const float*)d_in[11];
    float* out = (float*)d_out;

    const int* src = eidx;
    const int* dst = eidx + N_EDGES;
    char* ws = (char*)d_ws;

    int*          ocnt     = (int*)(ws + OCNT_OFF);
    unsigned int* oflow    = (unsigned int*)(ws + OFLOW_OFF);
    float*        partials = (float*)(ws + PART_OFF);
    float*        xw       = (float*)(ws + XW_OFF);
    int*          gslot    = (int*)(ws + GSLOT_OFF);

    hipMemsetAsync(ocnt, 0, sizeof(int), stream);
    hipMemsetAsync(gslot, 0xFF, GSLOT_BYTES, stream);   // pad = -1
    k_fill_xw<<<FILL_BLKS + XW_BLKS, 1024, 0, stream>>>(
        src, dst, gslot, ocnt, oflow, x, W, xw);
    k_agg<<<NBINS, 512, 0, stream>>>(
        gslot, ocnt, oflow, xw, bias, lin1_w, lin1_b,
        out_w, out_b, labels, weights, out, partials);
    k_loss_final<<<1, 512, 0, stream>>>(partials, out);
}